// Round 3
// baseline (242.757 us; speedup 1.0000x reference)
//
#include <hip/hip_runtime.h>
#include <hip/hip_bf16.h>

typedef __attribute__((ext_vector_type(8))) short bf16x8;
typedef __attribute__((ext_vector_type(4))) float f32x4;

#define MFMA16(a, b, c) __builtin_amdgcn_mfma_f32_16x16x32_bf16((a), (b), (c), 0, 0, 0)
#define ASYNC16(g, l)                                                     \
    __builtin_amdgcn_global_load_lds(                                     \
        (const __attribute__((address_space(1))) void*)(g),               \
        (__attribute__((address_space(3))) void*)(l), 16, 0, 0)

constexpr int B_ = 2, S_ = 2048, E_ = 1024, NH_ = 16, NKV_ = 4, HD_ = 64;

// ---------------------------------------------------------------------------
// fp32 -> bf16 conversion, flat 1D grid (no early-exit waste).
// ranges: [0,6144) q/k/v, [6144,6656) Wq, [6656,7168) Wo, [7168,7296) Wk,
// [7296,7424) Wv.
// ---------------------------------------------------------------------------
__global__ __launch_bounds__(256) void cvt_all(
    const float* __restrict__ s0, const float* __restrict__ s1,
    const float* __restrict__ s2, const float* __restrict__ s3,
    const float* __restrict__ s4, const float* __restrict__ s5,
    const float* __restrict__ s6,
    __hip_bfloat16* __restrict__ d0, __hip_bfloat16* __restrict__ d1,
    __hip_bfloat16* __restrict__ d2, __hip_bfloat16* __restrict__ d3,
    __hip_bfloat16* __restrict__ d4, __hip_bfloat16* __restrict__ d5,
    __hip_bfloat16* __restrict__ d6)
{
    int id = blockIdx.x;
    const float* s;
    __hip_bfloat16* d;
    if (id < 6144) {
        const int which = id >> 11;
        s = which == 0 ? s0 : (which == 1 ? s1 : s2);
        d = which == 0 ? d0 : (which == 1 ? d1 : d2);
        id &= 2047;
    } else if (id < 6656) { s = s3; d = d3; id -= 6144; }
    else if (id < 7168)   { s = s4; d = d4; id -= 6656; }
    else if (id < 7296)   { s = s5; d = d5; id -= 7168; }
    else                  { s = s6; d = d6; id -= 7296; }

    const size_t i = ((size_t)id * 256 + threadIdx.x) * 8;
    const float4 f0 = *reinterpret_cast<const float4*>(s + i);
    const float4 f1 = *reinterpret_cast<const float4*>(s + i + 4);
    union { __hip_bfloat16 h[8]; uint4 u; } t;
    t.h[0] = __float2bfloat16(f0.x); t.h[1] = __float2bfloat16(f0.y);
    t.h[2] = __float2bfloat16(f0.z); t.h[3] = __float2bfloat16(f0.w);
    t.h[4] = __float2bfloat16(f1.x); t.h[5] = __float2bfloat16(f1.y);
    t.h[6] = __float2bfloat16(f1.z); t.h[7] = __float2bfloat16(f1.w);
    *reinterpret_cast<uint4*>(d + i) = t.u;
}

// ---------------------------------------------------------------------------
// bf16 B^T GEMM core (UNCHANGED from 220 µs version): 128x128 tile, BK=64,
// global_load_lds (16B), 2-phase prefetch, T2 swizzle rule #21.
// ---------------------------------------------------------------------------
__device__ __forceinline__ void gemm_core(
    const __hip_bfloat16* __restrict__ A,
    const __hip_bfloat16* __restrict__ W,
    void* __restrict__ C,
    const int N, const int mode, const int m0, const int n0,
    __hip_bfloat16* sA, __hip_bfloat16* sW)
{
    const int tid  = threadIdx.x;
    const int l    = tid & 63;
    const int w    = tid >> 6;
    const int quad = l >> 4;
    const int lan  = l & 15;
    const int wm   = (w >> 1) * 64;
    const int wn   = (w & 1) * 64;

    const int srow  = w * 8 + (l >> 3);
    const int scolL = (l & 7) * 8;
    const int scolG = ((l & 7) ^ (l >> 3)) * 8;

    f32x4 acc[4][4] = {};

#define STAGE(buf, kb)                                                    \
    {                                                                     \
        _Pragma("unroll")                                                 \
        for (int q = 0; q < 4; ++q) {                                     \
            const int r_ = q * 32 + srow;                                 \
            ASYNC16(A + (size_t)(m0 + r_) * E_ + (kb) + scolG,            \
                    sA + (buf) * 8192 + r_ * 64 + scolL);                 \
            ASYNC16(W + (size_t)(n0 + r_) * E_ + (kb) + scolG,            \
                    sW + (buf) * 8192 + r_ * 64 + scolL);                 \
        }                                                                 \
    }

    STAGE(0, 0)
    int cur = 0;
#pragma unroll 1
    for (int t = 0; t < 16; ++t) {
        __syncthreads();
        if (t < 15) STAGE(cur ^ 1, (t + 1) * 64)

#pragma unroll
        for (int kk = 0; kk < 2; ++kk) {
            bf16x8 af[4], bf[4];
            const int ca = ((kk * 4 + quad) ^ (lan & 7)) * 8;
#pragma unroll
            for (int i = 0; i < 4; ++i)
                af[i] = *reinterpret_cast<const bf16x8*>(
                    sA + cur * 8192 + (wm + i * 16 + lan) * 64 + ca);
#pragma unroll
            for (int j = 0; j < 4; ++j)
                bf[j] = *reinterpret_cast<const bf16x8*>(
                    sW + cur * 8192 + (wn + j * 16 + lan) * 64 + ca);
#pragma unroll
            for (int i = 0; i < 4; ++i)
#pragma unroll
                for (int j = 0; j < 4; ++j)
                    acc[i][j] = MFMA16(af[i], bf[j], acc[i][j]);
        }
        cur ^= 1;
    }
#undef STAGE

#pragma unroll
    for (int i = 0; i < 4; ++i)
#pragma unroll
        for (int j = 0; j < 4; ++j)
#pragma unroll
            for (int r = 0; r < 4; ++r) {
                const int gm = m0 + wm + i * 16 + quad * 4 + r;
                const int gn = n0 + wn + j * 16 + lan;
                const float v = acc[i][j][r];
                if (mode == 2) {
                    ((float*)C)[(size_t)gm * N + gn] = v;
                } else {
                    const __hip_bfloat16 hv = __float2bfloat16(v);
                    if (mode == 0)
                        ((__hip_bfloat16*)C)[(size_t)gm * N + gn] = hv;
                    else  // V-transpose: [B,NKV,HD,S]
                        ((__hip_bfloat16*)C)
                            [((size_t)(gm >> 11) * N + gn) * (size_t)S_ +
                             (gm & 2047)] = hv;
                }
            }
}

__global__ __launch_bounds__(256) void gemm_qkv(
    const __hip_bfloat16* __restrict__ qb, const __hip_bfloat16* __restrict__ kb,
    const __hip_bfloat16* __restrict__ vb, const __hip_bfloat16* __restrict__ Wqb,
    const __hip_bfloat16* __restrict__ Wkb, const __hip_bfloat16* __restrict__ Wvb,
    __hip_bfloat16* __restrict__ QO, __hip_bfloat16* __restrict__ Kws,
    __hip_bfloat16* __restrict__ VT)
{
    __shared__ __hip_bfloat16 sA[2 * 8192];
    __shared__ __hip_bfloat16 sW[2 * 8192];
    int id = blockIdx.x;
    const __hip_bfloat16 *A, *W;
    void* C;
    int N, mode, bx, by;
    if (id < 256)      { A = qb; W = Wqb; C = QO;  N = 1024; mode = 0; bx = id & 7; by = id >> 3; }
    else if (id < 320) { id -= 256; A = kb; W = Wkb; C = Kws; N = 256; mode = 0; bx = id & 1; by = id >> 1; }
    else               { id -= 320; A = vb; W = Wvb; C = VT;  N = 256; mode = 1; bx = id & 1; by = id >> 1; }
    gemm_core(A, W, C, N, mode, by * 128, bx * 128, sA, sW);
}

__global__ __launch_bounds__(256) void gemm_out(
    const __hip_bfloat16* __restrict__ QO, const __hip_bfloat16* __restrict__ Wob,
    float* __restrict__ out)
{
    __shared__ __hip_bfloat16 sA[2 * 8192];
    __shared__ __hip_bfloat16 sW[2 * 8192];
    const int id = blockIdx.x;
    gemm_core(QO, Wob, out, 1024, 2, (id >> 3) * 128, (id & 7) * 128, sA, sW);
}

// ---------------------------------------------------------------------------
// Causal GQA flash attention r3: occupancy + conflict rewrite.
// - grid 32x16x2, ONE 64-row q-tile per block, LPT order (qt = 31-bx:
//   longest blocks dispatch first, short blocks backfill) -> 4096 waves
//   (was 2048), target ~16-20 waves/CU.
// - sK/sV stride 64 (no pad) + XOR slot swizzle (s ^= row&7) on write AND
//   read -> kills the 8-way bank conflict of the padded layout.
// - T13 defer-max: skip alpha-rescale unless row-max grew past 2^8.
// - T5 setprio(1) around both MFMA clusters.
// Per-wave math (swapped-QK, in-register softmax, bpermute P redistribution)
// identical to the verified r2 kernel.
// ---------------------------------------------------------------------------
__global__ __launch_bounds__(256) void attn(
    __hip_bfloat16* QO,
    const __hip_bfloat16* __restrict__ Kp,
    const __hip_bfloat16* __restrict__ VT)
{
    __shared__ __hip_bfloat16 sK[64][64];
    __shared__ __hip_bfloat16 sV[64][64];

    const int qt   = 31 - blockIdx.x;  // LPT schedule
    const int h    = blockIdx.y;
    const int b    = blockIdx.z;
    const int hk   = h >> 2;           // repeat_interleave mapping
    const int tid  = threadIdx.x;
    const int l    = tid & 63;
    const int w    = tid >> 6;
    const int quad = l >> 4;
    const int lan  = l & 15;
    const bool hi  = quad >= 2;
    const float KSC = 0.125f * 1.44269504088896340736f;

    // ds_bpermute byte indices for the P^T redistribution (verified r2).
    const int idxA = (((quad & 1) * 32) + lan) * 4;  // w2 = 0,1
    const int idxB = idxA + 64;                      // w2 = 2,3

    // staging: row kr, logical 16B slots s0,(s0+1); stored XOR-swizzled.
    const int kr  = tid >> 2;
    const int s0c = (tid & 3) * 2;
    const int sw0 = (s0c ^ (kr & 7)) * 8;        // swizzled elem offset
    const int sw1 = ((s0c + 1) ^ (kr & 7)) * 8;
    const int kc  = s0c * 8;                     // linear global elem offset

    const __hip_bfloat16* kg =
        Kp + ((size_t)((b * S_ + kr) * NKV_) + hk) * HD_ + kc;
    const __hip_bfloat16* vg =
        VT + ((size_t)((b * NKV_ + hk) * HD_) + kr) * S_ + kc;
    const size_t kstride = (size_t)64 * NKV_ * HD_;

    const int qr0 = qt * 64 + w * 16;
    const int qme = qr0 + lan;  // this lane's q-row

    const __hip_bfloat16* qp =
        QO + ((size_t)((b * S_ + qme) * NH_) + h) * HD_ + quad * 8;
    const bf16x8 aq0 = *reinterpret_cast<const bf16x8*>(qp);
    const bf16x8 aq1 = *reinterpret_cast<const bf16x8*>(qp + 32);

    float m_i = -3.0e38f, l_i = 0.f;
    f32x4 acc_o[4] = {};

    uint4 kv0 = *reinterpret_cast<const uint4*>(kg);
    uint4 kv1 = *reinterpret_cast<const uint4*>(kg + 8);
    uint4 vv0 = *reinterpret_cast<const uint4*>(vg);
    uint4 vv1 = *reinterpret_cast<const uint4*>(vg + 8);

    for (int kt = 0; kt <= qt; ++kt) {
        __syncthreads();  // staging overwrite vs prev iter's reads
        *reinterpret_cast<uint4*>(&sK[kr][sw0]) = kv0;
        *reinterpret_cast<uint4*>(&sK[kr][sw1]) = kv1;
        *reinterpret_cast<uint4*>(&sV[kr][sw0]) = vv0;
        *reinterpret_cast<uint4*>(&sV[kr][sw1]) = vv1;
        __syncthreads();

        if (kt < qt) {  // prefetch next K/V tile
            const __hip_bfloat16* kn = kg + (size_t)(kt + 1) * kstride;
            const __hip_bfloat16* vn = vg + (size_t)(kt + 1) * 64;
            kv0 = *reinterpret_cast<const uint4*>(kn);
            kv1 = *reinterpret_cast<const uint4*>(kn + 8);
            vv0 = *reinterpret_cast<const uint4*>(vn);
            vv1 = *reinterpret_cast<const uint4*>(vn + 8);
        }

        // S^T = K Q^T : accs[j][r] = S[q = qme][k = kt*64 + j*16 + quad*4 + r]
        f32x4 accs[4] = {};
        __builtin_amdgcn_s_setprio(1);
#pragma unroll
        for (int j = 0; j < 4; ++j) {
            const int swq0 = (quad ^ (lan & 7)) * 8;
            const int swq1 = ((4 + quad) ^ (lan & 7)) * 8;
            bf16x8 bk0 = *reinterpret_cast<const bf16x8*>(&sK[j * 16 + lan][swq0]);
            accs[j] = MFMA16(bk0, aq0, accs[j]);
            bf16x8 bk1 = *reinterpret_cast<const bf16x8*>(&sK[j * 16 + lan][swq1]);
            accs[j] = MFMA16(bk1, aq1, accs[j]);
        }
        __builtin_amdgcn_s_setprio(0);

        if (kt == qt) {  // causal mask on the diagonal tile
#pragma unroll
            for (int j = 0; j < 4; ++j)
#pragma unroll
                for (int r = 0; r < 4; ++r) {
                    const int kcg = kt * 64 + j * 16 + quad * 4 + r;
                    if (kcg > qme) accs[j][r] = -1e30f;
                }
        }

        // ---- per-lane online softmax (one q-row per lane) ----
        float tm = accs[0][0];
#pragma unroll
        for (int j = 0; j < 4; ++j)
#pragma unroll
            for (int r = 0; r < 4; ++r) tm = fmaxf(tm, accs[j][r]);
        tm = fmaxf(tm, __shfl_xor(tm, 16));
        tm = fmaxf(tm, __shfl_xor(tm, 32));

        // T13 defer-max: rescale only if the row max grew past 2^8.
        if (__any((tm - m_i) * KSC > 8.0f)) {
            const float mnew  = fmaxf(m_i, tm);
            const float alpha = exp2f((m_i - mnew) * KSC);
            l_i *= alpha;
            m_i  = mnew;
#pragma unroll
            for (int dd = 0; dd < 4; ++dd)
#pragma unroll
                for (int r = 0; r < 4; ++r) acc_o[dd][r] *= alpha;
        }

        float ps = 0.f;
#pragma unroll
        for (int j = 0; j < 4; ++j)
#pragma unroll
            for (int r = 0; r < 4; ++r) {
                const float p = exp2f((accs[j][r] - m_i) * KSC);
                accs[j][r] = p;
                ps += p;
            }
        ps += __shfl_xor(ps, 16);
        ps += __shfl_xor(ps, 32);
        l_i += ps;

        // ---- pack P to bf16 pairs ----
        uint pk[4][2];
#pragma unroll
        for (int j = 0; j < 4; ++j)
#pragma unroll
            for (int hh = 0; hh < 2; ++hh) {
                union { __hip_bfloat16 bh[2]; uint u; } t;
                t.bh[0] = __float2bfloat16(accs[j][2 * hh]);
                t.bh[1] = __float2bfloat16(accs[j][2 * hh + 1]);
                pk[j][hh] = t.u;
            }

        // ---- O^T += V^T P^T ----
#pragma unroll
        for (int kk = 0; kk < 2; ++kk) {
            union { uint u[4]; bf16x8 v; } pb;
#pragma unroll
            for (int w2 = 0; w2 < 4; ++w2) {
                const int idx = (w2 & 2) ? idxB : idxA;
                const uint a = (uint)__builtin_amdgcn_ds_bpermute(
                    idx, (int)pk[2 * kk][w2 & 1]);
                const uint bb = (uint)__builtin_amdgcn_ds_bpermute(
                    idx, (int)pk[2 * kk + 1][w2 & 1]);
                pb.u[w2] = hi ? bb : a;
            }
            __builtin_amdgcn_s_setprio(1);
#pragma unroll
            for (int dd = 0; dd < 4; ++dd) {
                const int swv = ((kk * 4 + quad) ^ (lan & 7)) * 8;
                bf16x8 av = *reinterpret_cast<const bf16x8*>(
                    &sV[dd * 16 + lan][swv]);
                acc_o[dd] = MFMA16(av, pb.v, acc_o[dd]);
            }
            __builtin_amdgcn_s_setprio(0);
        }
    }

    // ---- epilogue: O^T[d][q] -> QO[b, q, h, d], packed 8B stores ----
    const float inv = 1.0f / l_i;
    __hip_bfloat16* op =
        QO + ((size_t)((b * S_ + qme) * NH_) + h) * HD_ + quad * 4;
#pragma unroll
    for (int dd = 0; dd < 4; ++dd) {
        union { __hip_bfloat16 bh[4]; uint2 u; } t;
#pragma unroll
        for (int r = 0; r < 4; ++r)
            t.bh[r] = __float2bfloat16(acc_o[dd][r] * inv);
        *reinterpret_cast<uint2*>(op + dd * 16) = t.u;
    }
}

// ---------------------------------------------------------------------------
extern "C" void kernel_launch(void* const* d_in, const int* in_sizes, int n_in,
                              void* d_out, int out_size, void* d_ws, size_t ws_size,
                              hipStream_t stream) {
    // Contract (measured r1-r12): insertion order, all inputs f32,
    // mask(slot3)==tril, OUTPUT IS FLOAT32.
    const float* q  = (const float*)d_in[0];
    const float* k  = (const float*)d_in[1];
    const float* v  = (const float*)d_in[2];
    const float* Wq = (const float*)d_in[4];
    const float* Wk = (const float*)d_in[5];
    const float* Wv = (const float*)d_in[6];
    const float* Wo = (const float*)d_in[7];

    // workspace layout (bf16 elements), ~41 MB total
    __hip_bfloat16* ws = (__hip_bfloat16*)d_ws;
    __hip_bfloat16* qb   = ws;                    // 4M
    __hip_bfloat16* kb   = qb  + 4194304;         // 4M
    __hip_bfloat16* vb   = kb  + 4194304;         // 4M
    __hip_bfloat16* QO   = vb  + 4194304;         // 4M  [B,S,NH,HD]
    __hip_bfloat16* Kws  = QO  + 4194304;         // 1M  [B,S,NKV,HD]
    __hip_bfloat16* VT   = Kws + 1048576;         // 1M  [B,NKV,HD,S]
    __hip_bfloat16* Wqb  = VT  + 1048576;         // 1M
    __hip_bfloat16* Wob  = Wqb + 1048576;         // 1M
    __hip_bfloat16* Wkb  = Wob + 1048576;         // 256K
    __hip_bfloat16* Wvb  = Wkb + 262144;          // 256K

    cvt_all<<<dim3(7424), 256, 0, stream>>>(
        q, k, v, Wq, Wo, Wk, Wv, qb, kb, vb, Wqb, Wob, Wkb, Wvb);

    gemm_qkv<<<dim3(384), 256, 0, stream>>>(
        qb, kb, vb, Wqb, Wkb, Wvb, QO, Kws, VT);

    attn<<<dim3(32, NH_, B_), 256, 0, stream>>>(QO, Kws, VT);

    gemm_out<<<dim3(256), 256, 0, stream>>>(QO, Wob, (float*)d_out);
}

// Round 4
// 210.691 us; speedup vs baseline: 1.1522x; 1.1522x over previous
//
#include <hip/hip_runtime.h>
#include <hip/hip_bf16.h>

typedef __attribute__((ext_vector_type(8))) short bf16x8;
typedef __attribute__((ext_vector_type(4))) float f32x4;

#define MFMA16(a, b, c) __builtin_amdgcn_mfma_f32_16x16x32_bf16((a), (b), (c), 0, 0, 0)
#define ASYNC16(g, l)                                                     \
    __builtin_amdgcn_global_load_lds(                                     \
        (const __attribute__((address_space(1))) void*)(g),               \
        (__attribute__((address_space(3))) void*)(l), 16, 0, 0)

constexpr int B_ = 2, S_ = 2048, E_ = 1024, NH_ = 16, NKV_ = 4, HD_ = 64;

// ---------------------------------------------------------------------------
// fp32 -> bf16 conversion, flat 1D grid.
// ---------------------------------------------------------------------------
__global__ __launch_bounds__(256) void cvt_all(
    const float* __restrict__ s0, const float* __restrict__ s1,
    const float* __restrict__ s2, const float* __restrict__ s3,
    const float* __restrict__ s4, const float* __restrict__ s5,
    const float* __restrict__ s6,
    __hip_bfloat16* __restrict__ d0, __hip_bfloat16* __restrict__ d1,
    __hip_bfloat16* __restrict__ d2, __hip_bfloat16* __restrict__ d3,
    __hip_bfloat16* __restrict__ d4, __hip_bfloat16* __restrict__ d5,
    __hip_bfloat16* __restrict__ d6)
{
    int id = blockIdx.x;
    const float* s;
    __hip_bfloat16* d;
    if (id < 6144) {
        const int which = id >> 11;
        s = which == 0 ? s0 : (which == 1 ? s1 : s2);
        d = which == 0 ? d0 : (which == 1 ? d1 : d2);
        id &= 2047;
    } else if (id < 6656) { s = s3; d = d3; id -= 6144; }
    else if (id < 7168)   { s = s4; d = d4; id -= 6656; }
    else if (id < 7296)   { s = s5; d = d5; id -= 7168; }
    else                  { s = s6; d = d6; id -= 7296; }

    const size_t i = ((size_t)id * 256 + threadIdx.x) * 8;
    const float4 f0 = *reinterpret_cast<const float4*>(s + i);
    const float4 f1 = *reinterpret_cast<const float4*>(s + i + 4);
    union { __hip_bfloat16 h[8]; uint4 u; } t;
    t.h[0] = __float2bfloat16(f0.x); t.h[1] = __float2bfloat16(f0.y);
    t.h[2] = __float2bfloat16(f0.z); t.h[3] = __float2bfloat16(f0.w);
    t.h[4] = __float2bfloat16(f1.x); t.h[5] = __float2bfloat16(f1.y);
    t.h[6] = __float2bfloat16(f1.z); t.h[7] = __float2bfloat16(f1.w);
    *reinterpret_cast<uint4*>(d + i) = t.u;
}

// ---------------------------------------------------------------------------
// bf16 B^T GEMM core, r4: 64x128 tile (BM=64, BN=128), BK=64, gload_lds 16B,
// 2-phase prefetch, T2 swizzle rule #21. Smaller tile -> 2-3 blocks/CU so
// barrier drains overlap across blocks (m114), fixing the grid-starved
// 1-1.5 blocks/CU of the 128x128 version.
// Wave tile 32x64 (2x2 waves). LDS: sA 2x4096, sW 2x8192 elems (48 KB).
// ---------------------------------------------------------------------------
__device__ __forceinline__ void gemm_core(
    const __hip_bfloat16* __restrict__ A,
    const __hip_bfloat16* __restrict__ W,
    void* __restrict__ C,
    const int N, const int mode, const int m0, const int n0,
    __hip_bfloat16* sA, __hip_bfloat16* sW)
{
    const int tid  = threadIdx.x;
    const int l    = tid & 63;
    const int w    = tid >> 6;
    const int quad = l >> 4;
    const int lan  = l & 15;
    const int wm   = (w >> 1) * 32;
    const int wn   = (w & 1) * 64;

    // staging: per 32-row block wave w covers rows w*8..w*8+7; lane writes
    // LDS bytes base + l*16 (gload_lds contract: wave-uniform base + l*16).
    const int srow  = w * 8 + (l >> 3);
    const int scolL = (l & 7) * 8;                // linear LDS col (elems)
    const int scolG = ((l & 7) ^ (l >> 3)) * 8;   // inverse-swz global col

    f32x4 acc[2][4] = {};

#define STAGE(buf, kb)                                                    \
    {                                                                     \
        _Pragma("unroll")                                                 \
        for (int q = 0; q < 2; ++q) {                                     \
            const int r_ = q * 32 + srow;                                 \
            ASYNC16(A + (size_t)(m0 + r_) * E_ + (kb) + scolG,            \
                    sA + (buf) * 4096 + r_ * 64 + scolL);                 \
        }                                                                 \
        _Pragma("unroll")                                                 \
        for (int q = 0; q < 4; ++q) {                                     \
            const int r_ = q * 32 + srow;                                 \
            ASYNC16(W + (size_t)(n0 + r_) * E_ + (kb) + scolG,            \
                    sW + (buf) * 8192 + r_ * 64 + scolL);                 \
        }                                                                 \
    }

    STAGE(0, 0)
    int cur = 0;
#pragma unroll 1
    for (int t = 0; t < 16; ++t) {
        __syncthreads();  // implicit vmcnt(0): buf[cur] ready, buf[cur^1] free
        if (t < 15) STAGE(cur ^ 1, (t + 1) * 64)

#pragma unroll
        for (int kk = 0; kk < 2; ++kk) {
            bf16x8 af[2], bf[4];
            // swizzled read: chunk (kk*4+quad) of row r lives at slot
            // (kk*4+quad) ^ (r&7); r&7 == lan&7 for all fragment rows.
            const int ca = ((kk * 4 + quad) ^ (lan & 7)) * 8;
#pragma unroll
            for (int i = 0; i < 2; ++i)
                af[i] = *reinterpret_cast<const bf16x8*>(
                    sA + cur * 4096 + (wm + i * 16 + lan) * 64 + ca);
#pragma unroll
            for (int j = 0; j < 4; ++j)
                bf[j] = *reinterpret_cast<const bf16x8*>(
                    sW + cur * 8192 + (wn + j * 16 + lan) * 64 + ca);
#pragma unroll
            for (int i = 0; i < 2; ++i)
#pragma unroll
                for (int j = 0; j < 4; ++j)
                    acc[i][j] = MFMA16(af[i], bf[j], acc[i][j]);
        }
        cur ^= 1;
    }
#undef STAGE

#pragma unroll
    for (int i = 0; i < 2; ++i)
#pragma unroll
        for (int j = 0; j < 4; ++j)
#pragma unroll
            for (int r = 0; r < 4; ++r) {
                const int gm = m0 + wm + i * 16 + quad * 4 + r;
                const int gn = n0 + wn + j * 16 + lan;
                const float v = acc[i][j][r];
                if (mode == 2) {
                    ((float*)C)[(size_t)gm * N + gn] = v;
                } else {
                    const __hip_bfloat16 hv = __float2bfloat16(v);
                    if (mode == 0)
                        ((__hip_bfloat16*)C)[(size_t)gm * N + gn] = hv;
                    else  // V-transpose: [B,NKV,HD,S]
                        ((__hip_bfloat16*)C)
                            [((size_t)(gm >> 11) * N + gn) * (size_t)S_ +
                             (gm & 2047)] = hv;
                }
            }
}

// Fused Q/K/V projections, 64x128 tiles: blocks [0,512) = Q (64x8 tiles),
// [512,640) = K, [640,768) = V (transposed out). 768 blocks = 3/CU.
__global__ __launch_bounds__(256) void gemm_qkv(
    const __hip_bfloat16* __restrict__ qb, const __hip_bfloat16* __restrict__ kb,
    const __hip_bfloat16* __restrict__ vb, const __hip_bfloat16* __restrict__ Wqb,
    const __hip_bfloat16* __restrict__ Wkb, const __hip_bfloat16* __restrict__ Wvb,
    __hip_bfloat16* __restrict__ QO, __hip_bfloat16* __restrict__ Kws,
    __hip_bfloat16* __restrict__ VT)
{
    __shared__ __hip_bfloat16 sA[2 * 4096];
    __shared__ __hip_bfloat16 sW[2 * 8192];
    int id = blockIdx.x;
    const __hip_bfloat16 *A, *W;
    void* C;
    int N, mode, bx, by;
    if (id < 512)      { A = qb; W = Wqb; C = QO;  N = 1024; mode = 0; bx = id & 7; by = id >> 3; }
    else if (id < 640) { id -= 512; A = kb; W = Wkb; C = Kws; N = 256; mode = 0; bx = id & 1; by = id >> 1; }
    else               { id -= 640; A = vb; W = Wvb; C = VT;  N = 256; mode = 1; bx = id & 1; by = id >> 1; }
    gemm_core(A, W, C, N, mode, by * 64, bx * 128, sA, sW);
}

__global__ __launch_bounds__(256) void gemm_out(
    const __hip_bfloat16* __restrict__ QO, const __hip_bfloat16* __restrict__ Wob,
    float* __restrict__ out)
{
    __shared__ __hip_bfloat16 sA[2 * 4096];
    __shared__ __hip_bfloat16 sW[2 * 8192];
    const int id = blockIdx.x;   // 512 blocks: 64 x 8 tiles
    gemm_core(QO, Wob, out, 1024, 2, (id >> 3) * 64, (id & 7) * 128, sA, sW);
}

// ---------------------------------------------------------------------------
// Causal GQA flash attention r4 = r2 structure (69 µs verified: 2 q-tiles
// {bx, 31-bx} per block, grid 16x16x2) + the r3 pieces that the counters
// verified: stride-64 XOR-swizzled sK/sV (conflicts 6.5M -> 2.2M) and T13
// defer-max. setprio REMOVED (m190 case: barrier-locked waves, it starved
// siblings -> VALUBusy 50 -> 36 in r3).
// ---------------------------------------------------------------------------
__global__ __launch_bounds__(256) void attn(
    __hip_bfloat16* QO,
    const __hip_bfloat16* __restrict__ Kp,
    const __hip_bfloat16* __restrict__ VT)
{
    __shared__ __hip_bfloat16 sK[64][64];
    __shared__ __hip_bfloat16 sV[64][64];

    const int bx   = blockIdx.x;    // 0..15
    const int h    = blockIdx.y;
    const int b    = blockIdx.z;
    const int hk   = h >> 2;        // repeat_interleave mapping
    const int tid  = threadIdx.x;
    const int l    = tid & 63;
    const int w    = tid >> 6;
    const int quad = l >> 4;
    const int lan  = l & 15;
    const bool hi  = quad >= 2;
    const float KSC = 0.125f * 1.44269504088896340736f;

    // ds_bpermute byte indices for the P^T redistribution (verified r2).
    const int idxA = (((quad & 1) * 32) + lan) * 4;  // w2 = 0,1
    const int idxB = idxA + 64;                      // w2 = 2,3

    // staging: row kr, logical 16B slots s0c,(s0c+1); stored XOR-swizzled.
    const int kr  = tid >> 2;
    const int s0c = (tid & 3) * 2;
    const int sw0 = (s0c ^ (kr & 7)) * 8;        // swizzled elem offset
    const int sw1 = ((s0c + 1) ^ (kr & 7)) * 8;
    const int kc  = s0c * 8;                     // linear global elem offset

    // swizzled read offsets (row&7 == lan&7 for all fragment rows)
    const int swq0 = (quad ^ (lan & 7)) * 8;
    const int swq1 = ((4 + quad) ^ (lan & 7)) * 8;

    const __hip_bfloat16* kg =
        Kp + ((size_t)((b * S_ + kr) * NKV_) + hk) * HD_ + kc;
    const __hip_bfloat16* vg =
        VT + ((size_t)((b * NKV_ + hk) * HD_) + kr) * S_ + kc;
    const size_t kstride = (size_t)64 * NKV_ * HD_;

    for (int half = 0; half < 2; ++half) {
        const int qt  = half ? (31 - bx) : bx;
        const int qr0 = qt * 64 + w * 16;
        const int qme = qr0 + lan;  // this lane's q-row

        const __hip_bfloat16* qp =
            QO + ((size_t)((b * S_ + qme) * NH_) + h) * HD_ + quad * 8;
        const bf16x8 aq0 = *reinterpret_cast<const bf16x8*>(qp);
        const bf16x8 aq1 = *reinterpret_cast<const bf16x8*>(qp + 32);

        float m_i = -3.0e38f, l_i = 0.f;
        f32x4 acc_o[4] = {};

        uint4 kv0 = *reinterpret_cast<const uint4*>(kg);
        uint4 kv1 = *reinterpret_cast<const uint4*>(kg + 8);
        uint4 vv0 = *reinterpret_cast<const uint4*>(vg);
        uint4 vv1 = *reinterpret_cast<const uint4*>(vg + 8);

        for (int kt = 0; kt <= qt; ++kt) {
            __syncthreads();  // staging overwrite vs prev iter's reads
            *reinterpret_cast<uint4*>(&sK[kr][sw0]) = kv0;
            *reinterpret_cast<uint4*>(&sK[kr][sw1]) = kv1;
            *reinterpret_cast<uint4*>(&sV[kr][sw0]) = vv0;
            *reinterpret_cast<uint4*>(&sV[kr][sw1]) = vv1;
            __syncthreads();

            if (kt < qt) {  // prefetch next K/V tile
                const __hip_bfloat16* kn = kg + (size_t)(kt + 1) * kstride;
                const __hip_bfloat16* vn = vg + (size_t)(kt + 1) * 64;
                kv0 = *reinterpret_cast<const uint4*>(kn);
                kv1 = *reinterpret_cast<const uint4*>(kn + 8);
                vv0 = *reinterpret_cast<const uint4*>(vn);
                vv1 = *reinterpret_cast<const uint4*>(vn + 8);
            }

            // S^T = K Q^T : accs[j][r] = S[q=qme][k = kt*64 + j*16 + quad*4 + r]
            f32x4 accs[4] = {};
#pragma unroll
            for (int j = 0; j < 4; ++j) {
                bf16x8 bk0 = *reinterpret_cast<const bf16x8*>(&sK[j * 16 + lan][swq0]);
                accs[j] = MFMA16(bk0, aq0, accs[j]);
                bf16x8 bk1 = *reinterpret_cast<const bf16x8*>(&sK[j * 16 + lan][swq1]);
                accs[j] = MFMA16(bk1, aq1, accs[j]);
            }

            if (kt == qt) {  // causal mask on the diagonal tile
#pragma unroll
                for (int j = 0; j < 4; ++j)
#pragma unroll
                    for (int r = 0; r < 4; ++r) {
                        const int kcg = kt * 64 + j * 16 + quad * 4 + r;
                        if (kcg > qme) accs[j][r] = -1e30f;
                    }
            }

            // ---- per-lane online softmax (one q-row per lane) ----
            float tm = accs[0][0];
#pragma unroll
            for (int j = 0; j < 4; ++j)
#pragma unroll
                for (int r = 0; r < 4; ++r) tm = fmaxf(tm, accs[j][r]);
            tm = fmaxf(tm, __shfl_xor(tm, 16));
            tm = fmaxf(tm, __shfl_xor(tm, 32));

            // T13 defer-max: rescale only if the row max grew past 2^8.
            if (__any((tm - m_i) * KSC > 8.0f)) {
                const float mnew  = fmaxf(m_i, tm);
                const float alpha = exp2f((m_i - mnew) * KSC);
                l_i *= alpha;
                m_i  = mnew;
#pragma unroll
                for (int dd = 0; dd < 4; ++dd)
#pragma unroll
                    for (int r = 0; r < 4; ++r) acc_o[dd][r] *= alpha;
            }

            float ps = 0.f;
#pragma unroll
            for (int j = 0; j < 4; ++j)
#pragma unroll
                for (int r = 0; r < 4; ++r) {
                    const float p = exp2f((accs[j][r] - m_i) * KSC);
                    accs[j][r] = p;
                    ps += p;
                }
            ps += __shfl_xor(ps, 16);
            ps += __shfl_xor(ps, 32);
            l_i += ps;

            // ---- pack P to bf16 pairs ----
            uint pk[4][2];
#pragma unroll
            for (int j = 0; j < 4; ++j)
#pragma unroll
                for (int hh = 0; hh < 2; ++hh) {
                    union { __hip_bfloat16 bh[2]; uint u; } t;
                    t.bh[0] = __float2bfloat16(accs[j][2 * hh]);
                    t.bh[1] = __float2bfloat16(accs[j][2 * hh + 1]);
                    pk[j][hh] = t.u;
                }

            // ---- O^T += V^T P^T ----
#pragma unroll
            for (int kk = 0; kk < 2; ++kk) {
                union { uint u[4]; bf16x8 v; } pb;
#pragma unroll
                for (int w2 = 0; w2 < 4; ++w2) {
                    const int idx = (w2 & 2) ? idxB : idxA;
                    const uint a = (uint)__builtin_amdgcn_ds_bpermute(
                        idx, (int)pk[2 * kk][w2 & 1]);
                    const uint bb = (uint)__builtin_amdgcn_ds_bpermute(
                        idx, (int)pk[2 * kk + 1][w2 & 1]);
                    pb.u[w2] = hi ? bb : a;
                }
#pragma unroll
                for (int dd = 0; dd < 4; ++dd) {
                    const int swv = ((kk * 4 + quad) ^ (lan & 7)) * 8;
                    bf16x8 av = *reinterpret_cast<const bf16x8*>(
                        &sV[dd * 16 + lan][swv]);
                    acc_o[dd] = MFMA16(av, pb.v, acc_o[dd]);
                }
            }
        }

        // ---- epilogue: O^T[d][q] -> QO[b, q, h, d], packed 8B stores ----
        const float inv = 1.0f / l_i;
        __hip_bfloat16* op =
            QO + ((size_t)((b * S_ + qme) * NH_) + h) * HD_ + quad * 4;
#pragma unroll
        for (int dd = 0; dd < 4; ++dd) {
            union { __hip_bfloat16 bh[4]; uint2 u; } t;
#pragma unroll
            for (int r = 0; r < 4; ++r)
                t.bh[r] = __float2bfloat16(acc_o[dd][r] * inv);
            *reinterpret_cast<uint2*>(op + dd * 16) = t.u;
        }
    }
}

// ---------------------------------------------------------------------------
extern "C" void kernel_launch(void* const* d_in, const int* in_sizes, int n_in,
                              void* d_out, int out_size, void* d_ws, size_t ws_size,
                              hipStream_t stream) {
    // Contract (measured r1-r12): insertion order, all inputs f32,
    // mask(slot3)==tril, OUTPUT IS FLOAT32.
    const float* q  = (const float*)d_in[0];
    const float* k  = (const float*)d_in[1];
    const float* v  = (const float*)d_in[2];
    const float* Wq = (const float*)d_in[4];
    const float* Wk = (const float*)d_in[5];
    const float* Wv = (const float*)d_in[6];
    const float* Wo = (const float*)d_in[7];

    // workspace layout (bf16 elements), ~41 MB total
    __hip_bfloat16* ws = (__hip_bfloat16*)d_ws;
    __hip_bfloat16* qb   = ws;                    // 4M
    __hip_bfloat16* kb   = qb  + 4194304;         // 4M
    __hip_bfloat16* vb   = kb  + 4194304;         // 4M
    __hip_bfloat16* QO   = vb  + 4194304;         // 4M  [B,S,NH,HD]
    __hip_bfloat16* Kws  = QO  + 4194304;         // 1M  [B,S,NKV,HD]
    __hip_bfloat16* VT   = Kws + 1048576;         // 1M  [B,NKV,HD,S]
    __hip_bfloat16* Wqb  = VT  + 1048576;         // 1M
    __hip_bfloat16* Wob  = Wqb + 1048576;         // 1M
    __hip_bfloat16* Wkb  = Wob + 1048576;         // 256K
    __hip_bfloat16* Wvb  = Wkb + 262144;          // 256K

    cvt_all<<<dim3(7424), 256, 0, stream>>>(
        q, k, v, Wq, Wo, Wk, Wv, qb, kb, vb, Wqb, Wob, Wkb, Wvb);

    gemm_qkv<<<dim3(768), 256, 0, stream>>>(
        qb, kb, vb, Wqb, Wkb, Wvb, QO, Kws, VT);

    attn<<<dim3(16, NH_, B_), 256, 0, stream>>>(QO, Kws, VT);

    gemm_out<<<dim3(512), 256, 0, stream>>>(QO, Wob, (float*)d_out);
}